// Round 1
// 713.661 us; speedup vs baseline: 4.3136x; 4.3136x over previous
//
#include <hip/hip_runtime.h>
#include <stdint.h>

#define B_   16
#define MC   2048
#define MT   4096
#define E_   512
#define NRELS 69

typedef __attribute__((ext_vector_type(8))) short bf16x8;
typedef __attribute__((ext_vector_type(4))) float floatx4;

__device__ inline float b2f(ushort u) {
  union { uint32_t i; float f; } x; x.i = ((uint32_t)u) << 16; return x.f;
}
__device__ inline ushort f2b(float f) {
  union { float f; uint32_t u; } v; v.f = f;
  uint32_t r = (v.u + 0x7fffu + ((v.u >> 16) & 1u)) >> 16;
  return (ushort)r;
}

// ---------- dtype probe: fp32 data read as ushorts has random exponent bytes ----------
__global__ void detect_k(const ushort* __restrict__ t, int* __restrict__ flag) {
  int bad = 0;
  for (int j = threadIdx.x; j < 4096; j += 256) {
    int e = (t[j] >> 7) & 0xFF;          // bf16 exponent field
    if (e >= 0xC0) bad = 1;              // >= 2^65: impossible for 0.02-scale bf16
  }
  if (bad) atomicOr(flag, 1);
}

// ---------- normalize any float tensor to bf16 (copy or convert per flag) ----------
__global__ void cvt_k(const void* __restrict__ src, ushort* __restrict__ dst, int n8,
                      const int* __restrict__ flag) {
  int c = blockIdx.x * blockDim.x + threadIdx.x;   // chunk of 8 elements
  if (c >= n8) return;
  if (*flag) {
    const float* s = (const float*)src + (size_t)c * 8;
    float4 a = *(const float4*)s, b = *(const float4*)(s + 4);
    uint32_t p0 = (uint32_t)f2b(a.x) | ((uint32_t)f2b(a.y) << 16);
    uint32_t p1 = (uint32_t)f2b(a.z) | ((uint32_t)f2b(a.w) << 16);
    uint32_t p2 = (uint32_t)f2b(b.x) | ((uint32_t)f2b(b.y) << 16);
    uint32_t p3 = (uint32_t)f2b(b.z) | ((uint32_t)f2b(b.w) << 16);
    *(uint4*)(dst + (size_t)c * 8) = make_uint4(p0, p1, p2, p3);
  } else {
    *(uint4*)(dst + (size_t)c * 8) = *(const uint4*)((const ushort*)src + (size_t)c * 8);
  }
}

// ---------- gather h rows from concept_table (either dtype) -> bf16 dense ----------
__global__ void gather_h_k(const void* __restrict__ table, const int* __restrict__ ids,
                           ushort* __restrict__ out, int nrows, const int* __restrict__ flag) {
  int c = blockIdx.x * blockDim.x + threadIdx.x;   // chunk of 8
  int row = c >> 6;                                // 64 chunks per 512-col row
  if (row >= nrows) return;
  int col = (c & 63) << 3;
  int src = ids[row];
  if (*flag) {
    const float* s = (const float*)table + (size_t)src * E_ + col;
    float4 a = *(const float4*)s, b = *(const float4*)(s + 4);
    uint32_t p0 = (uint32_t)f2b(a.x) | ((uint32_t)f2b(a.y) << 16);
    uint32_t p1 = (uint32_t)f2b(a.z) | ((uint32_t)f2b(a.w) << 16);
    uint32_t p2 = (uint32_t)f2b(b.x) | ((uint32_t)f2b(b.y) << 16);
    uint32_t p3 = (uint32_t)f2b(b.z) | ((uint32_t)f2b(b.w) << 16);
    *(uint4*)(out + (size_t)row * E_ + col) = make_uint4(p0, p1, p2, p3);
  } else {
    *(uint4*)(out + (size_t)row * E_ + col) =
        *(const uint4*)((const ushort*)table + (size_t)src * E_ + col);
  }
}

// ---------- degree count (mask is hop-invariant); int counts feed CSR + inv ----------
__global__ void count_k(const int* __restrict__ head, const int* __restrict__ tail,
                        const int* __restrict__ labels, int* __restrict__ cnt) {
  int t = blockIdx.x * blockDim.x + threadIdx.x;
  if (t >= B_ * MT) return;
  if (labels[t] == -1) return;
  int b = t >> 12;
  atomicAdd(&cnt[b * MC + head[t]], 1);
  atomicAdd(&cnt[b * MC + tail[t]], 1);
}

__global__ void inv_k(const int* __restrict__ cnt, float* __restrict__ inv, int n) {
  int i = blockIdx.x * blockDim.x + threadIdx.x;
  if (i < n) {
    int c = cnt[i];
    inv[i] = 1.0f / (float)(c > 1 ? c : 1);
  }
}

// ---------- exclusive scan of 32768 counts -> offs[0..n], offs[n]=total ----------
__global__ void scan_k(const int* __restrict__ cnt, int* __restrict__ offs) {
  __shared__ int part[256];
  int tid = threadIdx.x;
  const int CH = (B_ * MC) / 256;   // 128
  int base = tid * CH, s = 0;
  for (int i = 0; i < CH; ++i) s += cnt[base + i];
  part[tid] = s;
  __syncthreads();
  for (int off = 1; off < 256; off <<= 1) {
    int v = (tid >= off) ? part[tid - off] : 0;
    __syncthreads();
    part[tid] += v;
    __syncthreads();
  }
  int run = (tid == 0) ? 0 : part[tid - 1];
  for (int i = 0; i < CH; ++i) { offs[base + i] = run; run += cnt[base + i]; }
  if (tid == 255) offs[B_ * MC] = run;
}

// ---------- CSR fill: one atomic per endpoint (~87K total, vs 89M before) ----------
__global__ void fill_k(const int* __restrict__ head, const int* __restrict__ tail,
                       const int* __restrict__ rid, const int* __restrict__ labels,
                       const int* __restrict__ offs, int* __restrict__ cursor,
                       int* __restrict__ edges) {
  int t = blockIdx.x * blockDim.x + threadIdx.x;
  if (t >= B_ * MT) return;
  if (labels[t] == -1) return;
  int b = t >> 12;
  int hb = b * MC + head[t], tb = b * MC + tail[t];
  int r = rid[t];
  int p = atomicAdd(&cursor[tb], 1);
  edges[offs[tb] + p] = head[t] | (r << 16);    // message head->tail
  p = atomicAdd(&cursor[hb], 1);
  edges[offs[hb] + p] = tail[t] | (r << 16);    // message tail->head
}

// ---------- gather messages: one wave per concept row; zero atomics ----------
// upd[row] = (sum over incident edges of h[other]-r) * inv[row], written ONCE as bf16.
__global__ void gather_msg_k(const ushort* __restrict__ h, const ushort* __restrict__ rtab,
                             const int* __restrict__ edges, const int* __restrict__ offs,
                             const float* __restrict__ inv, ushort* __restrict__ updb) {
  int row = blockIdx.x * 4 + (threadIdx.x >> 6);   // b*MC + c
  int lane = threadIdx.x & 63;
  int col = lane << 3;                             // 64 lanes x 8 cols = 512
  int beg = offs[row], end = offs[row + 1];
  int b = row >> 11;                               // MC = 2048
  float acc[8];
#pragma unroll
  for (int i = 0; i < 8; ++i) acc[i] = 0.f;
  const ushort* hbase = h + (size_t)b * MC * E_ + col;
  for (int e = beg; e < end; ++e) {
    int ent = edges[e];                            // uniform across wave -> broadcast
    int other = ent & 0xffff, rid = ent >> 16;
    uint4 vh = *(const uint4*)(hbase + (size_t)other * E_);   // coalesced 1KB row read
    uint4 vr = *(const uint4*)(rtab + (size_t)rid * E_ + col); // 69KB table: cache-hot
    uint32_t wh[4] = {vh.x, vh.y, vh.z, vh.w};
    uint32_t wr[4] = {vr.x, vr.y, vr.z, vr.w};
#pragma unroll
    for (int i = 0; i < 4; ++i) {
      acc[2 * i]     += b2f((ushort)(wh[i] & 0xffff)) - b2f((ushort)(wr[i] & 0xffff));
      acc[2 * i + 1] += b2f((ushort)(wh[i] >> 16))    - b2f((ushort)(wr[i] >> 16));
    }
  }
  float s = inv[row];
  uint32_t p[4];
#pragma unroll
  for (int i = 0; i < 4; ++i)
    p[i] = (uint32_t)f2b(acc[2 * i] * s) | ((uint32_t)f2b(acc[2 * i + 1] * s) << 16);
  *(uint4*)(updb + (size_t)row * E_ + col) = make_uint4(p[0], p[1], p[2], p[3]);
}

// ---------- tiny relation-table GEMM: out[NRELS x E] = in @ W^T (bf16 in/out) ----------
__global__ void rel_gemm_k(const ushort* __restrict__ in, const ushort* __restrict__ W,
                           ushort* __restrict__ outt) {
  __shared__ float arow[E_];
  int n = blockIdx.x;
  int tid = threadIdx.x;
  for (int k = tid; k < E_; k += 256) arow[k] = b2f(in[n * E_ + k]);
  __syncthreads();
#pragma unroll
  for (int c0 = 0; c0 < E_; c0 += 256) {
    int c = c0 + tid;
    float acc = 0.f;
    const ushort* wr = W + (size_t)c * E_;
    for (int k = 0; k < E_; k += 8) {
      uint4 w8 = *(const uint4*)(wr + k);
      uint32_t ww[4] = {w8.x, w8.y, w8.z, w8.w};
#pragma unroll
      for (int i = 0; i < 4; ++i) {
        acc += arow[k + 2 * i]     * b2f((ushort)(ww[i] & 0xffff));
        acc += arow[k + 2 * i + 1] * b2f((ushort)(ww[i] >> 16));
      }
    }
    outt[n * E_ + c] = f2b(acc);
  }
}

// ---------- fused h-GEMM: C = relu( A0@W0^T + A1@W1^T ), all-bf16 inputs ----------
#define BM 128
#define BN 128
#define BK 64
#define BKP 72  // padded LDS stride (shorts): 2-way bank alias only (free per m136)

__global__ __launch_bounds__(256) void gemm_h_k(
    const ushort* __restrict__ A0, const ushort* __restrict__ W0,
    const ushort* __restrict__ A1, const ushort* __restrict__ W1,
    ushort* __restrict__ C) {
  const int N = E_, K = E_;
  __shared__ ushort As[BM * BKP];
  __shared__ ushort Bs[BN * BKP];
  int nbn = N / BN;
  int bm = blockIdx.x / nbn, bn = blockIdx.x % nbn;
  int tid = threadIdx.x;
  int lane = tid & 63, wid = tid >> 6;
  int wm = (wid >> 1) * 64, wn = (wid & 1) * 64;
  int lrow = lane & 15, lq = lane >> 4;

  floatx4 acc[4][4];
#pragma unroll
  for (int i = 0; i < 4; ++i)
#pragma unroll
    for (int j = 0; j < 4; ++j) acc[i][j] = (floatx4)(0.0f);

  for (int pass = 0; pass < 2; ++pass) {
    const ushort* Am = pass ? A1 : A0;
    const ushort* Wm = pass ? W1 : W0;
    for (int k0 = 0; k0 < K; k0 += BK) {
#pragma unroll
      for (int i = 0; i < 4; ++i) {
        int c = tid + i * 256;
        int row = c >> 3, col = (c & 7) << 3;
        *(uint4*)(As + row * BKP + col) =
            *(const uint4*)(Am + (size_t)(bm * BM + row) * K + k0 + col);
      }
#pragma unroll
      for (int i = 0; i < 4; ++i) {
        int c = tid + i * 256;
        int row = c >> 3, col = (c & 7) << 3;
        *(uint4*)(Bs + row * BKP + col) =
            *(const uint4*)(Wm + (size_t)(bn * BN + row) * K + k0 + col);
      }
      __syncthreads();
#pragma unroll
      for (int kk = 0; kk < BK; kk += 32) {
        bf16x8 af[4], bfr[4];
#pragma unroll
        for (int mi = 0; mi < 4; ++mi)
          af[mi] = *(const bf16x8*)(As + (wm + mi * 16 + lrow) * BKP + kk + lq * 8);
#pragma unroll
        for (int ni = 0; ni < 4; ++ni)
          bfr[ni] = *(const bf16x8*)(Bs + (wn + ni * 16 + lrow) * BKP + kk + lq * 8);
#pragma unroll
        for (int mi = 0; mi < 4; ++mi)
#pragma unroll
          for (int ni = 0; ni < 4; ++ni)
            acc[mi][ni] = __builtin_amdgcn_mfma_f32_16x16x32_bf16(af[mi], bfr[ni], acc[mi][ni], 0, 0, 0);
      }
      __syncthreads();
    }
  }
  // C/D layout: col=lane&15, row=(lane>>4)*4+reg  [m89/m91 verified]
#pragma unroll
  for (int mi = 0; mi < 4; ++mi)
#pragma unroll
    for (int ni = 0; ni < 4; ++ni)
#pragma unroll
      for (int rg = 0; rg < 4; ++rg) {
        int row = bm * BM + wm + mi * 16 + lq * 4 + rg;
        int col = bn * BN + wn + ni * 16 + lrow;
        C[(size_t)row * N + col] = f2b(fmaxf(acc[mi][ni][rg], 0.0f));
      }
}

// ---------- output assembly: [h[head] | rtab2[rid] | h[tail]], dtype per flag ----------
__global__ void out_k(const ushort* __restrict__ h, const ushort* __restrict__ rtab,
                      const int* __restrict__ rid,
                      const int* __restrict__ head, const int* __restrict__ tail,
                      void* __restrict__ out, const int* __restrict__ flag) {
  int gid = blockIdx.x * blockDim.x + threadIdx.x;  // chunks of 8; B*MT*192 total
  int t = gid / 192;
  if (t >= B_ * MT) return;
  int sc = gid - t * 192;
  int sec = sc >> 6;
  int col = (sc & 63) << 3;
  int b = t >> 12;
  const ushort* src;
  if (sec == 0)      src = h + (size_t)(b * MC + head[t]) * E_ + col;
  else if (sec == 1) src = rtab + (size_t)rid[t] * E_ + col;
  else               src = h + (size_t)(b * MC + tail[t]) * E_ + col;
  size_t o = (size_t)t * 1536 + sec * 512 + col;
  if (*flag) {
    float* fo = (float*)out + o;
    uint4 v = *(const uint4*)src;
    uint32_t w[4] = {v.x, v.y, v.z, v.w};
    float4 f0, f1;
    f0.x = b2f((ushort)(w[0] & 0xffff)); f0.y = b2f((ushort)(w[0] >> 16));
    f0.z = b2f((ushort)(w[1] & 0xffff)); f0.w = b2f((ushort)(w[1] >> 16));
    f1.x = b2f((ushort)(w[2] & 0xffff)); f1.y = b2f((ushort)(w[2] >> 16));
    f1.z = b2f((ushort)(w[3] & 0xffff)); f1.w = b2f((ushort)(w[3] >> 16));
    *(float4*)fo = f0;
    *(float4*)(fo + 4) = f1;
  } else {
    *(uint4*)((ushort*)out + o) = *(const uint4*)src;
  }
}

extern "C" void kernel_launch(void* const* d_in, const int* in_sizes, int n_in,
                              void* d_out, int out_size, void* d_ws, size_t ws_size,
                              hipStream_t stream) {
  const void* concept_table  = d_in[0];
  const void* relation_table = d_in[1];
  const void* W_s = d_in[2];
  const void* W_n = d_in[3];
  const void* W_r = d_in[4];
  const int* concept_ids  = (const int*)d_in[5];
  const int* relation_ids = (const int*)d_in[6];
  const int* head_idx = (const int*)d_in[7];
  const int* tail_idx = (const int*)d_in[8];
  const int* labels   = (const int*)d_in[9];

  char* ws = (char*)d_ws;
  size_t off = 0;
  auto alloc = [&](size_t bytes) {
    char* p = ws + off;
    off += (bytes + 255) & ~(size_t)255;
    return p;
  };
  // ws total ~69 MB; 32 MB bf16 `upd` scratch lives in d_out (consumed before out_k)
  int*    flag   = (int*)   alloc(256);
  ushort* h_a    = (ushort*)alloc((size_t)B_ * MC * E_ * 2);   // 32 MB
  ushort* h_b    = (ushort*)alloc((size_t)B_ * MC * E_ * 2);   // 32 MB
  int*    cnt    = (int*)   alloc((size_t)B_ * MC * 4);        // 128 KB
  float*  inv    = (float*) alloc((size_t)B_ * MC * 4);        // 128 KB
  int*    offs   = (int*)   alloc(((size_t)B_ * MC + 1) * 4);  // 128 KB
  int*    cursor = (int*)   alloc((size_t)B_ * MC * 4);        // 128 KB
  int*    edges  = (int*)   alloc((size_t)2 * B_ * MT * 4);    // 512 KB
  ushort* Wsb    = (ushort*)alloc((size_t)2 * E_ * E_ * 2);    // 1 MB
  ushort* Wnb    = (ushort*)alloc((size_t)2 * E_ * E_ * 2);
  ushort* Wrb    = (ushort*)alloc((size_t)2 * E_ * E_ * 2);
  ushort* rtab0  = (ushort*)alloc((size_t)NRELS * E_ * 2);
  ushort* rtab1  = (ushort*)alloc((size_t)NRELS * E_ * 2);
  ushort* rtab2  = (ushort*)alloc((size_t)NRELS * E_ * 2);
  ushort* updb   = (ushort*)d_out;                             // 32 MB scratch in d_out

  // dtype probe
  hipMemsetAsync(flag, 0, 4, stream);
  detect_k<<<1, 256, 0, stream>>>((const ushort*)concept_table, flag);

  // normalize weights + relation table to bf16
  int nw8 = 2 * E_ * E_ / 8;
  cvt_k<<<(nw8 + 255) / 256, 256, 0, stream>>>(W_s, Wsb, nw8, flag);
  cvt_k<<<(nw8 + 255) / 256, 256, 0, stream>>>(W_n, Wnb, nw8, flag);
  cvt_k<<<(nw8 + 255) / 256, 256, 0, stream>>>(W_r, Wrb, nw8, flag);
  int nr8 = NRELS * E_ / 8;
  cvt_k<<<(nr8 + 255) / 256, 256, 0, stream>>>(relation_table, rtab0, nr8, flag);

  // gather h0 (dtype-aware source)
  gather_h_k<<<(B_ * MC * 64 + 255) / 256, 256, 0, stream>>>(concept_table, concept_ids, h_a,
                                                             B_ * MC, flag);

  // hop-invariant CSR incidence build: counts -> inv + exclusive scan -> fill
  hipMemsetAsync(cnt, 0, (size_t)B_ * MC * 4, stream);
  count_k<<<(B_ * MT + 255) / 256, 256, 0, stream>>>(head_idx, tail_idx, labels, cnt);
  inv_k<<<(B_ * MC + 255) / 256, 256, 0, stream>>>(cnt, inv, B_ * MC);
  scan_k<<<1, 256, 0, stream>>>(cnt, offs);
  hipMemsetAsync(cursor, 0, (size_t)B_ * MC * 4, stream);
  fill_k<<<(B_ * MT + 255) / 256, 256, 0, stream>>>(head_idx, tail_idx, relation_ids, labels,
                                                    offs, cursor, edges);

  // relation tables per hop: rtab1 = rtab0@Wr0^T, rtab2 = rtab1@Wr1^T
  rel_gemm_k<<<NRELS, 256, 0, stream>>>(rtab0, Wrb, rtab1);
  rel_gemm_k<<<NRELS, 256, 0, stream>>>(rtab1, Wrb + (size_t)E_ * E_, rtab2);

  // hop 0: gather messages (no atomics, single bf16 write/row), then fused GEMM
  gather_msg_k<<<B_ * MC / 4, 256, 0, stream>>>(h_a, rtab0, edges, offs, inv, updb);
  gemm_h_k<<<(B_ * MC / BM) * (E_ / BN), 256, 0, stream>>>(h_a, Wsb, updb, Wnb, h_b);

  // hop 1
  gather_msg_k<<<B_ * MC / 4, 256, 0, stream>>>(h_b, rtab1, edges, offs, inv, updb);
  gemm_h_k<<<(B_ * MC / BM) * (E_ / BN), 256, 0, stream>>>(h_b, Wsb + (size_t)E_ * E_, updb,
                                                           Wnb + (size_t)E_ * E_, h_a);

  out_k<<<(B_ * MT * 192 + 255) / 256, 256, 0, stream>>>(h_a, rtab2, relation_ids,
                                                         head_idx, tail_idx, d_out, flag);
}